// Round 2
// baseline (13003.905 us; speedup 1.0000x reference)
//
#include <hip/hip_runtime.h>
#include <hip/hip_bf16.h>
#include <math.h>

#define B_ 4
#define N_ 8192
#define MD_ 512
#define H_ 8
#define F_ 16
#define S_ 32
#define S3_ 32768
#define L_ 256
#define CO_ 152   // H*(F+3)
#define HF_ 128   // H*F
#define EPS_ 1e-5f

// ---------------- style projections: h = style @ W.T + b --------------------
__global__ __launch_bounds__(256) void style_proj(
    const float* __restrict__ style,
    const float* __restrict__ kw_w, const float* __restrict__ kw_b,
    const float* __restrict__ vw_w, const float* __restrict__ vw_b,
    const float* __restrict__ aw_w, const float* __restrict__ aw_b,
    float* __restrict__ hk, float* __restrict__ hv, float* __restrict__ ha) {
    int b = blockIdx.x;
    const float* st = style + b * L_;
    for (int r = threadIdx.x; r < 48 + 256 + 256; r += 256) {
        const float* wrow; float bias; float* dst; int j;
        if (r < 48)       { j = r;       wrow = kw_w + j * L_; bias = kw_b[j]; dst = hk + b * 48; }
        else if (r < 304) { j = r - 48;  wrow = vw_w + j * L_; bias = vw_b[j]; dst = hv + b * 256; }
        else              { j = r - 304; wrow = aw_w + j * L_; bias = aw_b[j]; dst = ha + b * 256; }
        float acc = bias;
        for (int l = 0; l < L_; ++l) acc = fmaf(st[l], wrow[l], acc);
        dst[j] = acc;
    }
}

// ---------------- conv-weight transpose to [h][tap][ic][oc] -----------------
__global__ __launch_bounds__(256) void wtrans_vm(const float* __restrict__ cw, float* __restrict__ wt) {
    int i = blockIdx.x * 256 + threadIdx.x;   // 8*27*16*16 = 55296 total
    int oc  = i & 15;
    int ic  = (i >> 4) & 15;
    int tap = (i >> 8) % 27;
    int h   = (i >> 8) / 27;
    wt[i] = cw[(((h * 16 + oc) * 16 + ic) * 27) + tap];
}

// ---------------- kv = W_kv @ input  (per batch) ----------------------------
__global__ __launch_bounds__(256) void kv_gemm(
    const float* __restrict__ input, const float* __restrict__ Wkv, float* __restrict__ kv) {
    int b = blockIdx.z, rb = blockIdx.y;
    int n0 = blockIdx.x * 1024 + (threadIdx.x << 2);
    __shared__ float wlds[19 * MD_];
    for (int i = threadIdx.x; i < 19 * MD_ / 4; i += 256)
        ((float4*)wlds)[i] = ((const float4*)(Wkv + rb * 19 * MD_))[i];
    __syncthreads();
    float acc[19][4];
    #pragma unroll
    for (int i = 0; i < 19; ++i)
        for (int q = 0; q < 4; ++q) acc[i][q] = 0.f;
    const float* inb = input + (size_t)b * MD_ * N_ + n0;
    for (int c = 0; c < MD_; ++c) {
        float4 x = *(const float4*)(inb + (size_t)c * N_);
        #pragma unroll
        for (int i = 0; i < 19; ++i) {
            float w = wlds[i * MD_ + c];
            acc[i][0] = fmaf(w, x.x, acc[i][0]);
            acc[i][1] = fmaf(w, x.y, acc[i][1]);
            acc[i][2] = fmaf(w, x.z, acc[i][2]);
            acc[i][3] = fmaf(w, x.w, acc[i][3]);
        }
    }
    float* outb = kv + (size_t)b * CO_ * N_ + n0;
    #pragma unroll
    for (int i = 0; i < 19; ++i)
        *(float4*)(outb + (size_t)(rb * 19 + i) * N_) =
            make_float4(acc[i][0], acc[i][1], acc[i][2], acc[i][3]);
}

// ---------------- per-(b,channel) mean / rsig over N ------------------------
__global__ __launch_bounds__(256) void stats_kernel(
    const float* __restrict__ x, float* __restrict__ mean, float* __restrict__ rsig) {
    int bc = blockIdx.x;
    const float* p = x + (size_t)bc * N_;
    float s = 0.f, s2 = 0.f;
    for (int i = threadIdx.x; i < N_; i += 256) {
        float v = p[i]; s += v; s2 = fmaf(v, v, s2);
    }
    #pragma unroll
    for (int off = 32; off; off >>= 1) { s += __shfl_down(s, off); s2 += __shfl_down(s2, off); }
    __shared__ float ls[4], ls2[4];
    int wid = threadIdx.x >> 6;
    if ((threadIdx.x & 63) == 0) { ls[wid] = s; ls2[wid] = s2; }
    __syncthreads();
    if (threadIdx.x == 0) {
        float S = ls[0] + ls[1] + ls[2] + ls[3];
        float S2 = ls2[0] + ls2[1] + ls2[2] + ls2[3];
        float mu = S * (1.f / N_);
        float var = S2 * (1.f / N_) - mu * mu;
        mean[bc] = mu;
        rsig[bc] = rsqrtf(var + EPS_);
    }
}

// ---------------- point prep: AdaIN + transform + tanh + interp -------------
// writes coordbuf (tt0,tt1,tt2, packed f0) and vbuf [bh][n][16] AdaIN'd values
__global__ __launch_bounds__(256) void point_prep(
    const float* __restrict__ kv, const float* __restrict__ mean_kv,
    const float* __restrict__ rsig_kv, const float* __restrict__ hk,
    const float* __restrict__ hv, const float* __restrict__ orig,
    const float* __restrict__ scale_p, const float* __restrict__ Tw,
    const float* __restrict__ Tb,
    float4* __restrict__ coordbuf, float* __restrict__ vbuf) {
    int p = blockIdx.x * 256 + threadIdx.x;
    int n = p & (N_ - 1);
    int bh = p >> 13;
    int h = bh & 7, b = bh >> 3;
    float scl = scale_p[0];

    float pt[3];
    #pragma unroll
    for (int j = 0; j < 3; ++j) {
        int c = h * 3 + j;
        float x  = kv[((size_t)(b * CO_ + c)) * N_ + n];
        float xn = (x - mean_kv[b * CO_ + c]) * rsig_kv[b * CO_ + c];
        float kr = fmaf(1.f + hk[b * 48 + c], xn, hk[b * 48 + 24 + c]);
        pt[j] = fmaf(scl, kr, orig[((size_t)(b * 3 + j)) * N_ + n]);
    }
    int f0[3]; float tt[3];
    #pragma unroll
    for (int i = 0; i < 3; ++i) {
        float key = Tb[h * 3 + i];
        #pragma unroll
        for (int j = 0; j < 3; ++j) key = fmaf(Tw[(h * 3 + i) * 3 + j], pt[j], key);
        float lat = tanhf(key);
        float g = (lat + 1.f) * 0.5f * (float)(S_ - 1);
        float ff = floorf(g);
        ff = fminf(fmaxf(ff, 0.f), 30.f);
        f0[i] = (int)ff;
        tt[i] = fminf(fmaxf(g - ff, 0.f), 1.f);
    }
    coordbuf[p] = make_float4(tt[0], tt[1], tt[2],
                              __int_as_float(f0[0] | (f0[1] << 5) | (f0[2] << 10)));
    float vf[16];
    #pragma unroll
    for (int f = 0; f < F_; ++f) {
        int c = 24 + h * F_ + f;
        float x  = kv[((size_t)(b * CO_ + c)) * N_ + n];
        float xn = (x - mean_kv[b * CO_ + c]) * rsig_kv[b * CO_ + c];
        int cv = h * F_ + f;
        vf[f] = fmaf(1.f + hv[b * 256 + cv], xn, hv[b * 256 + 128 + cv]);
    }
    float4* vb = (float4*)(vbuf + (size_t)p * 16);
    #pragma unroll
    for (int q = 0; q < 4; ++q)
        vb[q] = make_float4(vf[q * 4], vf[q * 4 + 1], vf[q * 4 + 2], vf[q * 4 + 3]);
}

// ---------------- splat via LDS privatization (no global atomics) -----------
// block -> one x-plane of one (b,h) lattice; 1024 blocks, 512 threads
__global__ __launch_bounds__(512) void splat_lds(
    const float4* __restrict__ coordbuf, const float* __restrict__ vbuf,
    float* __restrict__ z) {
    __shared__ float tile[16384];             // 32*32 voxels * 16 f, swizzled
    int logical = (blockIdx.x & 7) * 128 + (blockIdx.x >> 3);  // XCD swizzle (1024 = 8*128)
    int bh = logical >> 5;
    int x0 = logical & 31;
    for (int i = threadIdx.x; i < 16384; i += 512) tile[i] = 0.f;
    __syncthreads();
    const float4* cb = coordbuf + (size_t)bh * N_;
    const float* vb = vbuf + ((size_t)bh * N_) * 16;
    for (int n = threadIdx.x; n < N_; n += 512) {
        float4 c = cb[n];
        int pk = __float_as_int(c.w);
        int f0x = pk & 31;
        int cx;
        if (f0x == x0) cx = 0;
        else if (f0x == x0 - 1) cx = 1;
        else continue;
        float wx = cx ? c.x : 1.f - c.x;
        int f0y = (pk >> 5) & 31, f0z = (pk >> 10) & 31;
        const float4* vp = (const float4*)(vb + (size_t)n * 16);
        float4 v0 = vp[0], v1 = vp[1], v2 = vp[2], v3 = vp[3];
        float vf[16] = {v0.x, v0.y, v0.z, v0.w, v1.x, v1.y, v1.z, v1.w,
                        v2.x, v2.y, v2.z, v2.w, v3.x, v3.y, v3.z, v3.w};
        #pragma unroll
        for (int cy = 0; cy < 2; ++cy) {
            float wxy = wx * (cy ? c.y : 1.f - c.y);
            #pragma unroll
            for (int cz = 0; cz < 2; ++cz) {
                float w = wxy * (cz ? c.z : 1.f - c.z);
                int vox = ((f0y + cy) << 5) + f0z + cz;
                int base = vox << 4, rot = vox & 15;
                #pragma unroll
                for (int f = 0; f < 16; ++f)
                    unsafeAtomicAdd(&tile[base + ((f + rot) & 15)], vf[f] * w);
            }
        }
    }
    __syncthreads();
    float* zb = z + (((size_t)bh * S3_ + (x0 << 10)) << 4);
    for (int i = threadIdx.x; i < 16384; i += 512) {
        int vox = i >> 4, f = i & 15;
        zb[i] = tile[(vox << 4) + ((f + vox) & 15)];
    }
}

// ---------------- grouped 3x3x3 conv, voxel-major ---------------------------
// block 512 threads -> 512 voxels (half an x-plane); weights for its head in LDS
__global__ __launch_bounds__(512) void conv3d_vm(
    const float* __restrict__ z, const float* __restrict__ wt,
    const float* __restrict__ cbias, float* __restrict__ zc) {
    __shared__ float wlds[6912];              // 27 taps * 16 ic * 16 oc
    int logical = (blockIdx.x & 7) * 256 + (blockIdx.x >> 3);  // 2048 = 8*256
    int bh = logical >> 6;
    int part = logical & 63;
    int h = bh & 7;
    for (int i = threadIdx.x; i < 6912; i += 512) wlds[i] = wt[h * 6912 + i];
    __syncthreads();
    int vv = part * 512 + threadIdx.x;
    int xc = vv >> 10, yc = (vv >> 5) & 31, zd = vv & 31;
    const float* inb = z + ((size_t)bh << 19);   // 32768*16
    float acc[16];
    #pragma unroll
    for (int o = 0; o < 16; ++o) acc[o] = 0.f;
    #pragma unroll
    for (int dx = 0; dx < 3; ++dx) {
        int xx = xc + dx - 1;
        if (xx < 0 || xx > 31) continue;         // block-uniform
        #pragma unroll
        for (int dy = 0; dy < 3; ++dy) {
            int yy = yc + dy - 1;
            bool oky = (yy >= 0) && (yy <= 31);
            #pragma unroll
            for (int dz = 0; dz < 3; ++dz) {
                int zz = zd + dz - 1;
                bool ok = oky && (zz >= 0) && (zz <= 31);
                const float4* ip = (const float4*)(inb + ((size_t)(((xx << 5) + yy) * 32 + zz) << 4));
                float4 x0 = ok ? ip[0] : make_float4(0.f, 0.f, 0.f, 0.f);
                float4 x1 = ok ? ip[1] : make_float4(0.f, 0.f, 0.f, 0.f);
                float4 x2 = ok ? ip[2] : make_float4(0.f, 0.f, 0.f, 0.f);
                float4 x3 = ok ? ip[3] : make_float4(0.f, 0.f, 0.f, 0.f);
                float xin[16] = {x0.x, x0.y, x0.z, x0.w, x1.x, x1.y, x1.z, x1.w,
                                 x2.x, x2.y, x2.z, x2.w, x3.x, x3.y, x3.z, x3.w};
                const float4* wp = (const float4*)(wlds + ((dx * 3 + dy) * 3 + dz) * 256);
                #pragma unroll
                for (int ic = 0; ic < 16; ++ic) {
                    float xv = xin[ic];
                    float4 w0 = wp[ic * 4 + 0], w1 = wp[ic * 4 + 1];
                    float4 w2 = wp[ic * 4 + 2], w3 = wp[ic * 4 + 3];
                    acc[0]  = fmaf(xv, w0.x, acc[0]);  acc[1]  = fmaf(xv, w0.y, acc[1]);
                    acc[2]  = fmaf(xv, w0.z, acc[2]);  acc[3]  = fmaf(xv, w0.w, acc[3]);
                    acc[4]  = fmaf(xv, w1.x, acc[4]);  acc[5]  = fmaf(xv, w1.y, acc[5]);
                    acc[6]  = fmaf(xv, w1.z, acc[6]);  acc[7]  = fmaf(xv, w1.w, acc[7]);
                    acc[8]  = fmaf(xv, w2.x, acc[8]);  acc[9]  = fmaf(xv, w2.y, acc[9]);
                    acc[10] = fmaf(xv, w2.z, acc[10]); acc[11] = fmaf(xv, w2.w, acc[11]);
                    acc[12] = fmaf(xv, w3.x, acc[12]); acc[13] = fmaf(xv, w3.y, acc[13]);
                    acc[14] = fmaf(xv, w3.z, acc[14]); acc[15] = fmaf(xv, w3.w, acc[15]);
                }
            }
        }
    }
    float* ob = zc + ((size_t)bh << 19) + ((size_t)vv << 4);
    const float* bp = cbias + h * 16;
    #pragma unroll
    for (int q = 0; q < 4; ++q)
        ((float4*)ob)[q] = make_float4(acc[q*4] + bp[q*4], acc[q*4+1] + bp[q*4+1],
                                       acc[q*4+2] + bp[q*4+2], acc[q*4+3] + bp[q*4+3]);
}

// ---------------- slice: weighted gather back to points ---------------------
__global__ __launch_bounds__(256) void slice_vm(
    const float* __restrict__ zc, const float4* __restrict__ coordbuf,
    float* __restrict__ out) {
    int p = blockIdx.x * 256 + threadIdx.x;
    int n = p & (N_ - 1);
    int bh = p >> 13;
    int h = bh & 7, b = bh >> 3;
    float4 c = coordbuf[p];
    int pk = __float_as_int(c.w);
    int f0x = pk & 31, f0y = (pk >> 5) & 31, f0z = (pk >> 10) & 31;
    const float* gb = zc + ((size_t)bh << 19);
    float acc[16];
    #pragma unroll
    for (int f = 0; f < 16; ++f) acc[f] = 0.f;
    #pragma unroll
    for (int k = 0; k < 8; ++k) {
        int cx = (k >> 2) & 1, cy = (k >> 1) & 1, cz = k & 1;
        float w = (cx ? c.x : 1.f - c.x) * (cy ? c.y : 1.f - c.y) * (cz ? c.z : 1.f - c.z);
        int vox = (((f0x + cx) << 5) + f0y + cy) * 32 + f0z + cz;
        const float4* ip = (const float4*)(gb + ((size_t)vox << 4));
        float4 a0 = ip[0], a1 = ip[1], a2 = ip[2], a3 = ip[3];
        acc[0]  = fmaf(w, a0.x, acc[0]);  acc[1]  = fmaf(w, a0.y, acc[1]);
        acc[2]  = fmaf(w, a0.z, acc[2]);  acc[3]  = fmaf(w, a0.w, acc[3]);
        acc[4]  = fmaf(w, a1.x, acc[4]);  acc[5]  = fmaf(w, a1.y, acc[5]);
        acc[6]  = fmaf(w, a1.z, acc[6]);  acc[7]  = fmaf(w, a1.w, acc[7]);
        acc[8]  = fmaf(w, a2.x, acc[8]);  acc[9]  = fmaf(w, a2.y, acc[9]);
        acc[10] = fmaf(w, a2.z, acc[10]); acc[11] = fmaf(w, a2.w, acc[11]);
        acc[12] = fmaf(w, a3.x, acc[12]); acc[13] = fmaf(w, a3.y, acc[13]);
        acc[14] = fmaf(w, a3.z, acc[14]); acc[15] = fmaf(w, a3.w, acc[15]);
    }
    #pragma unroll
    for (int f = 0; f < 16; ++f)
        out[(((size_t)(b * HF_ + h * F_ + f)) << 13) + n] = acc[f];
}

// ---------------- final AdaIN + ReLU (in place on d_out) --------------------
__global__ __launch_bounds__(256) void final_adain(
    float* __restrict__ out, const float* __restrict__ mean_o,
    const float* __restrict__ rsig_o, const float* __restrict__ ha) {
    size_t i = (size_t)blockIdx.x * 256 + threadIdx.x;
    int bc = (int)(i >> 13);
    int c = bc & 127, b = bc >> 7;
    float x = out[i];
    float xn = (x - mean_o[bc]) * rsig_o[bc];
    float y = fmaf(1.f + ha[b * 256 + c], xn, ha[b * 256 + 128 + c]);
    out[i] = fmaxf(y, 0.f);
}

extern "C" void kernel_launch(void* const* d_in, const int* in_sizes, int n_in,
                              void* d_out, int out_size, void* d_ws, size_t ws_size,
                              hipStream_t stream) {
    (void)in_sizes; (void)n_in; (void)out_size; (void)ws_size;
    const float* input   = (const float*)d_in[0];
    const float* style   = (const float*)d_in[1];
    const float* orig    = (const float*)d_in[2];
    const float* Wkv     = (const float*)d_in[3];
    const float* kw_w    = (const float*)d_in[4];
    const float* kw_b    = (const float*)d_in[5];
    const float* vw_w    = (const float*)d_in[6];
    const float* vw_b    = (const float*)d_in[7];
    const float* aw_w    = (const float*)d_in[8];
    const float* aw_b    = (const float*)d_in[9];
    const float* scale_p = (const float*)d_in[10];
    const float* Tw      = (const float*)d_in[11];
    const float* Tb      = (const float*)d_in[12];
    const float* conv_w  = (const float*)d_in[13];
    const float* conv_b  = (const float*)d_in[14];
    float* out = (float*)d_out;

    // -------- workspace layout (floats), ~138.6 MB total --------------------
    float* ws = (float*)d_ws;
    float* z        = ws;                        // 16,777,216  (64MB) splat lattice
    float* zc       = ws + 16777216;             // 16,777,216  (64MB) conv output
    float* coordbuf = ws + 2 * 16777216;         //  1,048,576  (float4 per point)
    float* wt       = coordbuf + 1048576;        //     55,296
    float* ha       = wt + 55296;                //      1,024
    float* mean_o   = ha + 1024;                 //        512
    float* rsig_o   = mean_o + 512;              //        512
    float* mean_kv  = rsig_o + 512;              //        608
    float* rsig_kv  = mean_kv + 608;             //        608
    float* hk       = rsig_kv + 608;             //        192
    float* hv       = hk + 192;                  //      1,024
    // aliased into zc (dead until conv3d runs):
    float* vbuf = zc;                            //  4,194,304 (16MB) AdaIN'd values
    float* kv   = zc + 4194304;                  //  4,980,736 (19MB)

    style_proj<<<B_, 256, 0, stream>>>(style, kw_w, kw_b, vw_w, vw_b, aw_w, aw_b, hk, hv, ha);
    wtrans_vm<<<216, 256, 0, stream>>>(conv_w, wt);
    kv_gemm<<<dim3(8, 8, B_), 256, 0, stream>>>(input, Wkv, kv);
    stats_kernel<<<B_ * CO_, 256, 0, stream>>>(kv, mean_kv, rsig_kv);
    point_prep<<<B_ * H_ * N_ / 256, 256, 0, stream>>>(
        kv, mean_kv, rsig_kv, hk, hv, orig, scale_p, Tw, Tb,
        (float4*)coordbuf, vbuf);
    splat_lds<<<1024, 512, 0, stream>>>((const float4*)coordbuf, vbuf, z);
    conv3d_vm<<<2048, 512, 0, stream>>>(z, wt, conv_b, zc);
    slice_vm<<<B_ * H_ * N_ / 256, 256, 0, stream>>>(zc, (const float4*)coordbuf, out);
    stats_kernel<<<B_ * HF_, 256, 0, stream>>>(out, mean_o, rsig_o);
    final_adain<<<B_ * HF_ * N_ / 256, 256, 0, stream>>>(out, mean_o, rsig_o, ha);
}

// Round 3
// 579.832 us; speedup vs baseline: 22.4270x; 22.4270x over previous
//
#include <hip/hip_runtime.h>
#include <hip/hip_bf16.h>
#include <math.h>

#define B_ 4
#define N_ 8192
#define MD_ 512
#define H_ 8
#define F_ 16
#define S_ 32
#define S3_ 32768
#define L_ 256
#define CO_ 152   // H*(F+3)
#define HF_ 128   // H*F
#define EPS_ 1e-5f

// ---------------- style projections: h = style @ W.T + b --------------------
__global__ __launch_bounds__(256) void style_proj(
    const float* __restrict__ style,
    const float* __restrict__ kw_w, const float* __restrict__ kw_b,
    const float* __restrict__ vw_w, const float* __restrict__ vw_b,
    const float* __restrict__ aw_w, const float* __restrict__ aw_b,
    float* __restrict__ hk, float* __restrict__ hv, float* __restrict__ ha) {
    int b = blockIdx.x;
    const float* st = style + b * L_;
    for (int r = threadIdx.x; r < 48 + 256 + 256; r += 256) {
        const float* wrow; float bias; float* dst; int j;
        if (r < 48)       { j = r;       wrow = kw_w + j * L_; bias = kw_b[j]; dst = hk + b * 48; }
        else if (r < 304) { j = r - 48;  wrow = vw_w + j * L_; bias = vw_b[j]; dst = hv + b * 256; }
        else              { j = r - 304; wrow = aw_w + j * L_; bias = aw_b[j]; dst = ha + b * 256; }
        float acc = bias;
        for (int l = 0; l < L_; ++l) acc = fmaf(st[l], wrow[l], acc);
        dst[j] = acc;
    }
}

// ---------------- conv-weight transpose to [h][tap][ic][oc] -----------------
__global__ __launch_bounds__(256) void wtrans_vm(const float* __restrict__ cw, float* __restrict__ wt) {
    int i = blockIdx.x * 256 + threadIdx.x;   // 8*27*16*16 = 55296 total
    int oc  = i & 15;
    int ic  = (i >> 4) & 15;
    int tap = (i >> 8) % 27;
    int h   = (i >> 8) / 27;
    wt[i] = cw[(((h * 16 + oc) * 16 + ic) * 27) + tap];
}

// ---------------- kv = W_kv @ input  (per batch) ----------------------------
__global__ __launch_bounds__(256) void kv_gemm(
    const float* __restrict__ input, const float* __restrict__ Wkv, float* __restrict__ kv) {
    int b = blockIdx.z, rb = blockIdx.y;
    int n0 = blockIdx.x * 1024 + (threadIdx.x << 2);
    __shared__ float wlds[19 * MD_];
    for (int i = threadIdx.x; i < 19 * MD_ / 4; i += 256)
        ((float4*)wlds)[i] = ((const float4*)(Wkv + rb * 19 * MD_))[i];
    __syncthreads();
    float acc[19][4];
    #pragma unroll
    for (int i = 0; i < 19; ++i)
        for (int q = 0; q < 4; ++q) acc[i][q] = 0.f;
    const float* inb = input + (size_t)b * MD_ * N_ + n0;
    for (int c = 0; c < MD_; ++c) {
        float4 x = *(const float4*)(inb + (size_t)c * N_);
        #pragma unroll
        for (int i = 0; i < 19; ++i) {
            float w = wlds[i * MD_ + c];
            acc[i][0] = fmaf(w, x.x, acc[i][0]);
            acc[i][1] = fmaf(w, x.y, acc[i][1]);
            acc[i][2] = fmaf(w, x.z, acc[i][2]);
            acc[i][3] = fmaf(w, x.w, acc[i][3]);
        }
    }
    float* outb = kv + (size_t)b * CO_ * N_ + n0;
    #pragma unroll
    for (int i = 0; i < 19; ++i)
        *(float4*)(outb + (size_t)(rb * 19 + i) * N_) =
            make_float4(acc[i][0], acc[i][1], acc[i][2], acc[i][3]);
}

// ---------------- per-(b,channel) mean / rsig over N ------------------------
__global__ __launch_bounds__(256) void stats_kernel(
    const float* __restrict__ x, float* __restrict__ mean, float* __restrict__ rsig) {
    int bc = blockIdx.x;
    const float* p = x + (size_t)bc * N_;
    float s = 0.f, s2 = 0.f;
    for (int i = threadIdx.x; i < N_; i += 256) {
        float v = p[i]; s += v; s2 = fmaf(v, v, s2);
    }
    #pragma unroll
    for (int off = 32; off; off >>= 1) { s += __shfl_down(s, off); s2 += __shfl_down(s2, off); }
    __shared__ float ls[4], ls2[4];
    int wid = threadIdx.x >> 6;
    if ((threadIdx.x & 63) == 0) { ls[wid] = s; ls2[wid] = s2; }
    __syncthreads();
    if (threadIdx.x == 0) {
        float S = ls[0] + ls[1] + ls[2] + ls[3];
        float S2 = ls2[0] + ls2[1] + ls2[2] + ls2[3];
        float mu = S * (1.f / N_);
        float var = S2 * (1.f / N_) - mu * mu;
        mean[bc] = mu;
        rsig[bc] = rsqrtf(var + EPS_);
    }
}

// ---------------- point prep: AdaIN + transform + tanh + interp -------------
__global__ __launch_bounds__(256) void point_prep(
    const float* __restrict__ kv, const float* __restrict__ mean_kv,
    const float* __restrict__ rsig_kv, const float* __restrict__ hk,
    const float* __restrict__ hv, const float* __restrict__ orig,
    const float* __restrict__ scale_p, const float* __restrict__ Tw,
    const float* __restrict__ Tb,
    float4* __restrict__ coordbuf, float* __restrict__ vbuf) {
    int p = blockIdx.x * 256 + threadIdx.x;
    int n = p & (N_ - 1);
    int bh = p >> 13;
    int h = bh & 7, b = bh >> 3;
    float scl = scale_p[0];

    float pt[3];
    #pragma unroll
    for (int j = 0; j < 3; ++j) {
        int c = h * 3 + j;
        float x  = kv[((size_t)(b * CO_ + c)) * N_ + n];
        float xn = (x - mean_kv[b * CO_ + c]) * rsig_kv[b * CO_ + c];
        float kr = fmaf(1.f + hk[b * 48 + c], xn, hk[b * 48 + 24 + c]);
        pt[j] = fmaf(scl, kr, orig[((size_t)(b * 3 + j)) * N_ + n]);
    }
    int f0[3]; float tt[3];
    #pragma unroll
    for (int i = 0; i < 3; ++i) {
        float key = Tb[h * 3 + i];
        #pragma unroll
        for (int j = 0; j < 3; ++j) key = fmaf(Tw[(h * 3 + i) * 3 + j], pt[j], key);
        float lat = tanhf(key);
        float g = (lat + 1.f) * 0.5f * (float)(S_ - 1);
        float ff = floorf(g);
        ff = fminf(fmaxf(ff, 0.f), 30.f);
        f0[i] = (int)ff;
        tt[i] = fminf(fmaxf(g - ff, 0.f), 1.f);
    }
    coordbuf[p] = make_float4(tt[0], tt[1], tt[2],
                              __int_as_float(f0[0] | (f0[1] << 5) | (f0[2] << 10)));
    float vf[16];
    #pragma unroll
    for (int f = 0; f < F_; ++f) {
        int c = 24 + h * F_ + f;
        float x  = kv[((size_t)(b * CO_ + c)) * N_ + n];
        float xn = (x - mean_kv[b * CO_ + c]) * rsig_kv[b * CO_ + c];
        int cv = h * F_ + f;
        vf[f] = fmaf(1.f + hv[b * 256 + cv], xn, hv[b * 256 + 128 + cv]);
    }
    float4* vb = (float4*)(vbuf + (size_t)p * 16);
    #pragma unroll
    for (int q = 0; q < 4; ++q)
        vb[q] = make_float4(vf[q * 4], vf[q * 4 + 1], vf[q * 4 + 2], vf[q * 4 + 3]);
}

// ---------------- splat via LDS privatization (no global atomics) -----------
__global__ __launch_bounds__(512) void splat_lds(
    const float4* __restrict__ coordbuf, const float* __restrict__ vbuf,
    float* __restrict__ z) {
    __shared__ float tile[16384];             // 32*32 voxels * 16 f, swizzled
    int logical = (blockIdx.x & 7) * 128 + (blockIdx.x >> 3);  // XCD swizzle (1024 = 8*128)
    int bh = logical >> 5;
    int x0 = logical & 31;
    for (int i = threadIdx.x; i < 16384; i += 512) tile[i] = 0.f;
    __syncthreads();
    const float4* cb = coordbuf + (size_t)bh * N_;
    const float* vb = vbuf + ((size_t)bh * N_) * 16;
    for (int n = threadIdx.x; n < N_; n += 512) {
        float4 c = cb[n];
        int pk = __float_as_int(c.w);
        int f0x = pk & 31;
        int cx;
        if (f0x == x0) cx = 0;
        else if (f0x == x0 - 1) cx = 1;
        else continue;
        float wx = cx ? c.x : 1.f - c.x;
        int f0y = (pk >> 5) & 31, f0z = (pk >> 10) & 31;
        const float4* vp = (const float4*)(vb + (size_t)n * 16);
        float4 v0 = vp[0], v1 = vp[1], v2 = vp[2], v3 = vp[3];
        float vf[16] = {v0.x, v0.y, v0.z, v0.w, v1.x, v1.y, v1.z, v1.w,
                        v2.x, v2.y, v2.z, v2.w, v3.x, v3.y, v3.z, v3.w};
        #pragma unroll
        for (int cy = 0; cy < 2; ++cy) {
            float wxy = wx * (cy ? c.y : 1.f - c.y);
            #pragma unroll
            for (int cz = 0; cz < 2; ++cz) {
                float w = wxy * (cz ? c.z : 1.f - c.z);
                int vox = ((f0y + cy) << 5) + f0z + cz;
                int base = vox << 4, rot = vox & 15;
                #pragma unroll
                for (int f = 0; f < 16; ++f)
                    unsafeAtomicAdd(&tile[base + ((f + rot) & 15)], vf[f] * w);
            }
        }
    }
    __syncthreads();
    float* zb = z + (((size_t)bh * S3_ + (x0 << 10)) << 4);
    for (int i = threadIdx.x; i < 16384; i += 512) {
        int vox = i >> 4, f = i & 15;
        zb[i] = tile[(vox << 4) + ((f + vox) & 15)];
    }
}

// ---------------- grouped 3x3x3 conv, voxel-major, no-spill -----------------
// tap loop NOT unrolled: bounded live registers. Weights read via wave-uniform
// address (scalarizes to s_load / broadcast L1); no LDS staging.
__global__ __launch_bounds__(512) void conv3d_vm(
    const float* __restrict__ z, const float* __restrict__ wt,
    const float* __restrict__ cbias, float* __restrict__ zc) {
    int logical = (blockIdx.x & 7) * 256 + (blockIdx.x >> 3);  // 2048 = 8*256
    int bh = logical >> 6;
    int part = logical & 63;
    int h = bh & 7;
    int vv = part * 512 + threadIdx.x;
    int xc = vv >> 10, yc = (vv >> 5) & 31, zd = vv & 31;
    const float* inb = z + ((size_t)bh << 19);   // 32768*16
    const float* wg = wt + h * 6912;
    float acc[16];
    #pragma unroll
    for (int o = 0; o < 16; ++o) acc[o] = 0.f;
    #pragma unroll 1
    for (int tap = 0; tap < 27; ++tap) {
        int dx = tap / 9, r9 = tap - dx * 9;
        int dy = r9 / 3, dz = r9 - dy * 3;
        int xx = xc + dx - 1, yy = yc + dy - 1, zz = zd + dz - 1;
        bool ok = (xx >= 0) & (xx <= 31) & (yy >= 0) & (yy <= 31) & (zz >= 0) & (zz <= 31);
        const float4* ip = (const float4*)(inb + ((size_t)((((xx << 5) + yy) << 5) + zz) << 4));
        float4 x0, x1, x2, x3;
        if (ok) { x0 = ip[0]; x1 = ip[1]; x2 = ip[2]; x3 = ip[3]; }
        else {
            x0 = make_float4(0.f, 0.f, 0.f, 0.f); x1 = x0; x2 = x0; x3 = x0;
        }
        float xin[16] = {x0.x, x0.y, x0.z, x0.w, x1.x, x1.y, x1.z, x1.w,
                         x2.x, x2.y, x2.z, x2.w, x3.x, x3.y, x3.z, x3.w};
        const float4* wp = (const float4*)(wg + tap * 256);
        #pragma unroll
        for (int ic = 0; ic < 16; ++ic) {
            float xv = xin[ic];
            float4 w0 = wp[ic * 4 + 0], w1 = wp[ic * 4 + 1];
            float4 w2 = wp[ic * 4 + 2], w3 = wp[ic * 4 + 3];
            acc[0]  = fmaf(xv, w0.x, acc[0]);  acc[1]  = fmaf(xv, w0.y, acc[1]);
            acc[2]  = fmaf(xv, w0.z, acc[2]);  acc[3]  = fmaf(xv, w0.w, acc[3]);
            acc[4]  = fmaf(xv, w1.x, acc[4]);  acc[5]  = fmaf(xv, w1.y, acc[5]);
            acc[6]  = fmaf(xv, w1.z, acc[6]);  acc[7]  = fmaf(xv, w1.w, acc[7]);
            acc[8]  = fmaf(xv, w2.x, acc[8]);  acc[9]  = fmaf(xv, w2.y, acc[9]);
            acc[10] = fmaf(xv, w2.z, acc[10]); acc[11] = fmaf(xv, w2.w, acc[11]);
            acc[12] = fmaf(xv, w3.x, acc[12]); acc[13] = fmaf(xv, w3.y, acc[13]);
            acc[14] = fmaf(xv, w3.z, acc[14]); acc[15] = fmaf(xv, w3.w, acc[15]);
        }
    }
    float* ob = zc + ((size_t)bh << 19) + ((size_t)vv << 4);
    const float* bp = cbias + h * 16;
    #pragma unroll
    for (int q = 0; q < 4; ++q)
        ((float4*)ob)[q] = make_float4(acc[q*4] + bp[q*4], acc[q*4+1] + bp[q*4+1],
                                       acc[q*4+2] + bp[q*4+2], acc[q*4+3] + bp[q*4+3]);
}

// ---------------- slice: weighted gather back to points ---------------------
__global__ __launch_bounds__(256) void slice_vm(
    const float* __restrict__ zc, const float4* __restrict__ coordbuf,
    float* __restrict__ out) {
    int p = blockIdx.x * 256 + threadIdx.x;
    int n = p & (N_ - 1);
    int bh = p >> 13;
    int h = bh & 7, b = bh >> 3;
    float4 c = coordbuf[p];
    int pk = __float_as_int(c.w);
    int f0x = pk & 31, f0y = (pk >> 5) & 31, f0z = (pk >> 10) & 31;
    const float* gb = zc + ((size_t)bh << 19);
    float acc[16];
    #pragma unroll
    for (int f = 0; f < 16; ++f) acc[f] = 0.f;
    #pragma unroll 1
    for (int k = 0; k < 8; ++k) {
        int cx = (k >> 2) & 1, cy = (k >> 1) & 1, cz = k & 1;
        float w = (cx ? c.x : 1.f - c.x) * (cy ? c.y : 1.f - c.y) * (cz ? c.z : 1.f - c.z);
        int vox = (((f0x + cx) << 5) + f0y + cy) * 32 + f0z + cz;
        const float4* ip = (const float4*)(gb + ((size_t)vox << 4));
        float4 a0 = ip[0], a1 = ip[1], a2 = ip[2], a3 = ip[3];
        acc[0]  = fmaf(w, a0.x, acc[0]);  acc[1]  = fmaf(w, a0.y, acc[1]);
        acc[2]  = fmaf(w, a0.z, acc[2]);  acc[3]  = fmaf(w, a0.w, acc[3]);
        acc[4]  = fmaf(w, a1.x, acc[4]);  acc[5]  = fmaf(w, a1.y, acc[5]);
        acc[6]  = fmaf(w, a1.z, acc[6]);  acc[7]  = fmaf(w, a1.w, acc[7]);
        acc[8]  = fmaf(w, a2.x, acc[8]);  acc[9]  = fmaf(w, a2.y, acc[9]);
        acc[10] = fmaf(w, a2.z, acc[10]); acc[11] = fmaf(w, a2.w, acc[11]);
        acc[12] = fmaf(w, a3.x, acc[12]); acc[13] = fmaf(w, a3.y, acc[13]);
        acc[14] = fmaf(w, a3.z, acc[14]); acc[15] = fmaf(w, a3.w, acc[15]);
    }
    #pragma unroll
    for (int f = 0; f < 16; ++f)
        out[(((size_t)(b * HF_ + h * F_ + f)) << 13) + n] = acc[f];
}

// ---------------- final AdaIN + ReLU (in place on d_out) --------------------
__global__ __launch_bounds__(256) void final_adain(
    float* __restrict__ out, const float* __restrict__ mean_o,
    const float* __restrict__ rsig_o, const float* __restrict__ ha) {
    size_t i = (size_t)blockIdx.x * 256 + threadIdx.x;
    int bc = (int)(i >> 13);
    int c = bc & 127, b = bc >> 7;
    float x = out[i];
    float xn = (x - mean_o[bc]) * rsig_o[bc];
    float y = fmaf(1.f + ha[b * 256 + c], xn, ha[b * 256 + 128 + c]);
    out[i] = fmaxf(y, 0.f);
}

extern "C" void kernel_launch(void* const* d_in, const int* in_sizes, int n_in,
                              void* d_out, int out_size, void* d_ws, size_t ws_size,
                              hipStream_t stream) {
    (void)in_sizes; (void)n_in; (void)out_size; (void)ws_size;
    const float* input   = (const float*)d_in[0];
    const float* style   = (const float*)d_in[1];
    const float* orig    = (const float*)d_in[2];
    const float* Wkv     = (const float*)d_in[3];
    const float* kw_w    = (const float*)d_in[4];
    const float* kw_b    = (const float*)d_in[5];
    const float* vw_w    = (const float*)d_in[6];
    const float* vw_b    = (const float*)d_in[7];
    const float* aw_w    = (const float*)d_in[8];
    const float* aw_b    = (const float*)d_in[9];
    const float* scale_p = (const float*)d_in[10];
    const float* Tw      = (const float*)d_in[11];
    const float* Tb      = (const float*)d_in[12];
    const float* conv_w  = (const float*)d_in[13];
    const float* conv_b  = (const float*)d_in[14];
    float* out = (float*)d_out;

    // -------- workspace layout (floats), ~138.6 MB total --------------------
    float* ws = (float*)d_ws;
    float* z        = ws;                        // 16,777,216  (64MB) splat lattice
    float* zc       = ws + 16777216;             // 16,777,216  (64MB) conv output
    float* coordbuf = ws + 2 * 16777216;         //  1,048,576  (float4 per point)
    float* wt       = coordbuf + 1048576;        //     55,296
    float* ha       = wt + 55296;                //      1,024
    float* mean_o   = ha + 1024;                 //        512
    float* rsig_o   = mean_o + 512;              //        512
    float* mean_kv  = rsig_o + 512;              //        608
    float* rsig_kv  = mean_kv + 608;             //        608
    float* hk       = rsig_kv + 608;             //        192
    float* hv       = hk + 192;                  //      1,024
    // aliased into zc (dead until conv3d runs):
    float* vbuf = zc;                            //  4,194,304 (16MB) AdaIN'd values
    float* kv   = zc + 4194304;                  //  4,980,736 (19MB)

    style_proj<<<B_, 256, 0, stream>>>(style, kw_w, kw_b, vw_w, vw_b, aw_w, aw_b, hk, hv, ha);
    wtrans_vm<<<216, 256, 0, stream>>>(conv_w, wt);
    kv_gemm<<<dim3(8, 8, B_), 256, 0, stream>>>(input, Wkv, kv);
    stats_kernel<<<B_ * CO_, 256, 0, stream>>>(kv, mean_kv, rsig_kv);
    point_prep<<<B_ * H_ * N_ / 256, 256, 0, stream>>>(
        kv, mean_kv, rsig_kv, hk, hv, orig, scale_p, Tw, Tb,
        (float4*)coordbuf, vbuf);
    splat_lds<<<1024, 512, 0, stream>>>((const float4*)coordbuf, vbuf, z);
    conv3d_vm<<<2048, 512, 0, stream>>>(z, wt, conv_b, zc);
    slice_vm<<<B_ * H_ * N_ / 256, 256, 0, stream>>>(zc, (const float4*)coordbuf, out);
    stats_kernel<<<B_ * HF_, 256, 0, stream>>>(out, mean_o, rsig_o);
    final_adain<<<B_ * HF_ * N_ / 256, 256, 0, stream>>>(out, mean_o, rsig_o, ha);
}